// Round 1
// baseline (143801.648 us; speedup 1.0000x reference)
//
#include <hip/hip_runtime.h>
#include <stdint.h>

#define DEV __device__ __forceinline__

namespace {

constexpr int kT = 512, kB = 32, kF = 128, kHE = 512, kHD = 512, kA = 256;
constexpr int kNB = 512, kNT = 256;

// ---- workspace layout (float offsets) ----
constexpr size_t oWencAll = 0;                            // [2048][640]  = [Wih|Whh] rows
constexpr size_t oWdecC   = oWencAll + 2048ull*640;       // [2048][1024] = [Wih_ctx | Wih_h + Whh]
constexpr size_t oEncSt   = oWdecC   + 2048ull*1024;      // [32][512][512] encoder states
constexpr size_t oEncPr   = oEncSt   + (size_t)kB*kT*kHE; // [32][512][256] enc_proj (+Wenc_b)
constexpr size_t oHenc    = oEncPr   + (size_t)kB*kT*kA;  // [2][32][512]
constexpr size_t oHdec    = oHenc    + 2ull*kB*kHE;       // [2][32][512]
constexpr size_t oCtx     = oHdec    + 2ull*kB*kHD;       // [2][32][512]
constexpr size_t oLog     = oCtx     + 2ull*kB*kHE;       // [32][512]
constexpr size_t oScp     = oLog     + (size_t)kB*kT;     // [32][16][256] dscore partials
constexpr size_t oEbias   = oScp     + (size_t)kB*16*kA;  // 2048
constexpr size_t oDbias   = oEbias   + 2048;              // 2048
constexpr size_t oAb2     = oDbias   + 2048;              // 256 (Wdec_b + attn_bias)
constexpr size_t oEnd     = oAb2     + 256;
// ints at ws+oEnd: [0..31] fullbar grp, [32] root, [33] gen, [34] abort,
// [40..43] EG(encoder), [48..79] AB1, [80..111] AB2, [112..143] CA

struct SmemEnc { float xh[8][644]; float zbuf[256][2]; float zs[8][4][4]; };
struct SmemEP  { float4 et[32][32]; };
struct SmemA   { float h[32]; float sc[256]; float v[256]; };
struct SmemB   { float l[512]; float red[4]; float4 cb[32][9]; };
struct SmemC   { float xt[2][16][132]; float zb[128][2]; };
union Smem { SmemEnc enc; SmemEP ep; SmemA pa; SmemB pb; SmemC pc; };

DEV float frcp(float x){ return __builtin_amdgcn_rcpf(x); }
DEV float fsig(float x){ return frcp(1.f + __expf(-x)); }
DEV float ftanh(float x){ return 1.f - 2.f*frcp(__expf(2.f*x) + 1.f); }

DEV int ld_acq(int* p){ return __hip_atomic_load(p, __ATOMIC_ACQUIRE, __HIP_MEMORY_SCOPE_AGENT); }

DEV void spin_ge(int* p, int tgt, int* abortf){
  int g = 0;
  while (ld_acq(p) < tgt){
    if (__hip_atomic_load(abortf, __ATOMIC_RELAXED, __HIP_MEMORY_SCOPE_AGENT) != 0) break;
    if (++g > (1<<22)){ __hip_atomic_store(abortf, 1, __ATOMIC_RELAXED, __HIP_MEMORY_SCOPE_AGENT); break; }
    __builtin_amdgcn_s_sleep(2);
  }
}

// arrive (release) + wait until counter >= tgt   (monotone counters: no reset races)
DEV void mini_bar(int* p, int tgt, int* abortf){
  __syncthreads();
  if (threadIdx.x == 0){
    __threadfence();
    __hip_atomic_fetch_add(p, 1, __ATOMIC_RELEASE, __HIP_MEMORY_SCOPE_AGENT);
    spin_ge(p, tgt, abortf);
  }
  __syncthreads();
}
DEV void mini_wait(int* p, int tgt, int* abortf){
  __syncthreads();
  if (threadIdx.x == 0) spin_ge(p, tgt, abortf);
  __syncthreads();
}
DEV void mini_arrive(int* p){
  __syncthreads();
  if (threadIdx.x == 0){
    __threadfence();
    __hip_atomic_fetch_add(p, 1, __ATOMIC_RELEASE, __HIP_MEMORY_SCOPE_AGENT);
  }
}

// two-level 512-block barrier (32 groups x 16), sense via generation counter
DEV void fullbar(int* ctr){
  __syncthreads();
  if (threadIdx.x == 0){
    int* gcnt = ctr; int* root = ctr+32; int* gen = ctr+33; int* abortf = ctr+34;
    int g = __hip_atomic_load(gen, __ATOMIC_RELAXED, __HIP_MEMORY_SCOPE_AGENT);
    __threadfence();
    int grp = blockIdx.x >> 4;
    bool last = false;
    if (__hip_atomic_fetch_add(&gcnt[grp], 1, __ATOMIC_ACQ_REL, __HIP_MEMORY_SCOPE_AGENT) == 15){
      __hip_atomic_store(&gcnt[grp], 0, __ATOMIC_RELAXED, __HIP_MEMORY_SCOPE_AGENT);
      if (__hip_atomic_fetch_add(root, 1, __ATOMIC_ACQ_REL, __HIP_MEMORY_SCOPE_AGENT) == 31){
        __hip_atomic_store(root, 0, __ATOMIC_RELAXED, __HIP_MEMORY_SCOPE_AGENT);
        __hip_atomic_fetch_add(gen, 1, __ATOMIC_RELEASE, __HIP_MEMORY_SCOPE_AGENT);
        last = true;
      }
    }
    if (!last){
      int gd = 0;
      while (__hip_atomic_load(gen, __ATOMIC_ACQUIRE, __HIP_MEMORY_SCOPE_AGENT) == g){
        if (__hip_atomic_load(abortf, __ATOMIC_RELAXED, __HIP_MEMORY_SCOPE_AGENT) != 0) break;
        if (++gd > (1<<22)){ __hip_atomic_store(abortf, 1, __ATOMIC_RELAXED, __HIP_MEMORY_SCOPE_AGENT); break; }
        __builtin_amdgcn_s_sleep(2);
      }
    }
  }
  __syncthreads();
}

} // namespace

__global__ __launch_bounds__(kNT, 2) void bahdanau_kernel(
    const float* __restrict__ x,
    const float* __restrict__ eWih, const float* __restrict__ eWhh,
    const float* __restrict__ eBih, const float* __restrict__ eBhh,
    const float* __restrict__ WencW, const float* __restrict__ WencB,
    const float* __restrict__ WdecW, const float* __restrict__ WdecB,
    const float* __restrict__ Vw, const float* __restrict__ attnB,
    const float* __restrict__ dWih, const float* __restrict__ dWhh,
    const float* __restrict__ dBih, const float* __restrict__ dBhh,
    float* __restrict__ out, float* __restrict__ ws, int* __restrict__ ctr)
{
  __shared__ Smem sm;
  const int tid = threadIdx.x;
  const int bid = blockIdx.x;

  float* wencall = ws + oWencAll;
  float* wdecc   = ws + oWdecC;
  float* encst   = ws + oEncSt;
  float* encpr   = ws + oEncPr;
  float* henc    = ws + oHenc;
  float* hdec    = ws + oHdec;
  float* ctxb    = ws + oCtx;
  float* logbuf  = ws + oLog;
  float* scp     = ws + oScp;
  float* ebias   = ws + oEbias;
  float* dbias   = ws + oDbias;
  float* ab2w    = ws + oAb2;
  int* abortf    = ctr + 34;

  // ---------------- init (all independent, grid-stride) ----------------
  {
    const int gid = bid*kNT + tid;
    const int stride = kNB*kNT;
    for (int i=gid; i<2048*640; i+=stride){
      int col = i/640, k = i - col*640;
      wencall[i] = (k < kF) ? eWih[col*kF + k] : eWhh[(size_t)col*kHE + (k-kF)];
    }
    for (int i=gid; i<2048*1024; i+=stride){
      int col = i>>10, k = i&1023;
      float v2 = dWih[((size_t)col<<10) + k];
      if (k >= 512) v2 += dWhh[((size_t)col<<9) + (k-512)];
      wdecc[i] = v2;
    }
    for (int i=gid; i<2048; i+=stride){ ebias[i] = eBih[i]+eBhh[i]; dbias[i] = dBih[i]+dBhh[i]; }
    for (int i=gid; i<256; i+=stride){ ab2w[i] = WdecB[i]+attnB[i]; }
    for (int i=gid; i<kB*kHE; i+=stride) henc[i] = 0.f;
    for (int i=gid; i<kB*kHD; i+=stride){
      int e = i & 511;
      float zi = dBih[e]+dBhh[e];
      float zg = dBih[1024+e]+dBhh[1024+e];
      float zo = dBih[1536+e]+dBhh[1536+e];
      float c0 = fsig(zi)*ftanh(zg);
      hdec[i] = fsig(zo)*ftanh(c0);   // parity-0 initial decoder h (same all b)
    }
  }
  fullbar(ctr);

  // ---------------- encoder: 512 steps, per-b-group mini-barrier ----------------
  {
    const int bg = bid >> 7;          // 4 groups of 8 batch rows
    const int ec = bid & 127;         // 128 e-chunks of 4
    const int b0 = bg*8, e0 = ec*4;
    const int ks  = tid >> 7;         // K-split half
    const int r   = tid & 127;
    const int e_l = r & 3, gate = (r>>2)&3, b_l = r>>4;
    const int col = gate*kHE + e0 + e_l;
    const float4* wr = (const float4*)(wencall + (size_t)col*640);
    const int srow = tid >> 5, sj = tid & 31;
    int p = 0;
    float creg = 0.f;
    for (int t=0; t<kT; ++t){
      { // stage [x_t ; h_{t-1}] for 8 rows into LDS (padded 644 to spread banks)
        const float4* xsrc = (const float4*)(x) + ((size_t)(b0+srow)*kT + t)*32;
        float4* dst = (float4*)(&sm.enc.xh[srow][0]);
        dst[sj] = xsrc[sj];
        const float4* hsrc = (const float4*)(henc + (size_t)p*kB*kHE) + (size_t)(b0+srow)*128;
        #pragma unroll
        for (int it=0; it<4; ++it) dst[32 + sj + it*32] = hsrc[sj + it*32];
      }
      __syncthreads();
      {
        const float4* xv = (const float4*)(&sm.enc.xh[b_l][0]) + ks*80;
        const float4* wv = wr + ks*80;
        float a0=0,a1=0,a2=0,a3=0;
        #pragma unroll 8
        for (int q=0;q<80;++q){
          float4 w = wv[q]; float4 v2 = xv[q];
          a0 += w.x*v2.x; a1 += w.y*v2.y; a2 += w.z*v2.z; a3 += w.w*v2.w;
        }
        sm.enc.zbuf[r][ks] = (a0+a1)+(a2+a3);
      }
      __syncthreads();
      if (tid < 128){
        float z = sm.enc.zbuf[tid][0] + sm.enc.zbuf[tid][1] + ebias[col];
        sm.enc.zs[b_l][gate][e_l] = z;
      }
      __syncthreads();
      if (tid < 32){
        int bl2 = tid>>2, el2 = tid&3;
        float zi = sm.enc.zs[bl2][0][el2];
        float zf = sm.enc.zs[bl2][1][el2];
        float zg = sm.enc.zs[bl2][2][el2];
        float zo = sm.enc.zs[bl2][3][el2];
        float c2 = fsig(zf)*creg + fsig(zi)*ftanh(zg);
        creg = c2;
        float h = fsig(zo)*ftanh(c2);
        int b = b0 + bl2, e = e0 + el2;
        henc[(size_t)(p^1)*kB*kHE + (size_t)b*kHE + e] = h;
        encst[((size_t)b*kT + t)*kHE + e] = h;
      }
      mini_bar(&ctr[40+bg], 128*(t+1), abortf);
      p ^= 1;
    }
  }
  fullbar(ctr);

  // ---------------- enc_proj = enc_states @ Wenc^T + b (one-time GEMM) ----------------
  {
    const int r0 = bid*32;
    const int a = tid;
    float acc[32];
    #pragma unroll
    for (int i=0;i<32;++i) acc[i]=0.f;
    for (int kt=0; kt<4; ++kt){
      #pragma unroll
      for (int i2=0;i2<4;++i2){
        int q = tid + i2*256;
        int row = q>>5, qi = q&31;
        sm.ep.et[row][qi] = ((const float4*)(encst + ((size_t)(r0+row))*kHE + kt*128))[qi];
      }
      __syncthreads();
      const float4* wv = (const float4*)(WencW + (size_t)a*kHE + kt*128);
      #pragma unroll 1
      for (int q=0;q<32;++q){
        float4 w = wv[q];
        #pragma unroll
        for (int i=0;i<32;++i){
          float4 e4 = sm.ep.et[i][q];
          acc[i] += e4.x*w.x + e4.y*w.y + e4.z*w.z + e4.w*w.w;
        }
      }
      __syncthreads();
    }
    float bb = WencB[a];
    #pragma unroll
    for (int i=0;i<32;++i) encpr[((size_t)(r0+i))*kA + a] = acc[i] + bb;
  }
  fullbar(ctr);

  // ---------------- decoder: 512 steps ----------------
  {
    const int bA = bid >> 4, tc = bid & 15, t0a = tc*32;   // A/B roles: (batch b, chunk)
    const int ecB = bid & 15;
    const int bgC = bid >> 8, ecp = bid & 255, e0c = ecp*2; // C role: (b-group of 16, e-pair)
    const int col_l = tid & 127, ksC = tid >> 7;
    const int e_lC = col_l & 1, gateC = (col_l>>1)&3, b_lC = col_l>>3;
    const int colC = gateC*kHD + e0c + e_lC;
    const float4* wrC = (const float4*)(wdecc + (size_t)colC*1024);
    int* cCAw  = &ctr[112 + (bA>>4)*16 + tc];
    int* cCAa  = &ctr[112 + bgC*16 + (ecp>>4)];
    int* cAB1  = &ctr[48 + bA];
    int* cAB2  = &ctr[80 + bA];
    float cregD = 0.f;
    if (tid < 32){
      int e = e0c + (tid&1);
      cregD = fsig(dbias[e])*ftanh(dbias[1024+e]);  // c0 (same for all b)
    }
    int p = 0;
    for (int t=0; t<kT; ++t){
      // ---- phase A: dscore partial + share + logits ----
      mini_wait(cCAw, 16*t, abortf);              // h slice [tc*32,+32) from C_{t-1}
      if (tid < 32) sm.pa.h[tid] = hdec[(size_t)p*kB*kHD + (size_t)bA*kHD + t0a + tid];
      sm.pa.v[tid] = Vw[tid];
      __syncthreads();
      {
        float sp = 0.f;
        const float4* wv = (const float4*)(WdecW + (size_t)tid*kHD + t0a);
        #pragma unroll
        for (int q=0;q<8;++q){
          float4 w = wv[q];
          sp += w.x*sm.pa.h[q*4+0] + w.y*sm.pa.h[q*4+1] + w.z*sm.pa.h[q*4+2] + w.w*sm.pa.h[q*4+3];
        }
        scp[((size_t)bA*16 + tc)*kA + tid] = sp;
      }
      mini_bar(cAB1, 16*(t+1), abortf);
      {
        float sc = ab2w[tid];
        #pragma unroll
        for (int j=0;j<16;++j) sc += scp[((size_t)bA*16 + j)*kA + tid];
        sm.pa.sc[tid] = sc;
      }
      __syncthreads();
      {
        const int tl = tid>>3, as = tid&7;
        const float4* ep4 = (const float4*)(encpr + ((size_t)bA*kT + t0a + tl)*kA);
        float acc = 0.f;
        #pragma unroll
        for (int q=0;q<8;++q){
          float4 e4 = ep4[q*8 + as];
          int a0 = q*32 + as*4;
          acc += sm.pa.v[a0+0]*ftanh(e4.x + sm.pa.sc[a0+0]);
          acc += sm.pa.v[a0+1]*ftanh(e4.y + sm.pa.sc[a0+1]);
          acc += sm.pa.v[a0+2]*ftanh(e4.z + sm.pa.sc[a0+2]);
          acc += sm.pa.v[a0+3]*ftanh(e4.w + sm.pa.sc[a0+3]);
        }
        acc += __shfl_down(acc, 4, 8);
        acc += __shfl_down(acc, 2, 8);
        acc += __shfl_down(acc, 1, 8);
        if (as == 0) logbuf[(size_t)bA*kT + t0a + tl] = acc;  // V_b dropped: softmax-invariant
      }
      mini_bar(cAB2, 16*(t+1), abortf);
      // ---- phase B: softmax (no max-sub; |logit|<=~8) + context ----
      {
        float l0 = logbuf[(size_t)bA*kT + tid];
        float l1 = logbuf[(size_t)bA*kT + 256 + tid];
        float p0 = __expf(l0), p1 = __expf(l1);
        sm.pb.l[tid] = p0; sm.pb.l[tid+256] = p1;
        float psum = p0 + p1;
        #pragma unroll
        for (int off=32; off; off>>=1) psum += __shfl_down(psum, off, 64);
        if ((tid&63)==0) sm.pb.red[tid>>6] = psum;
        __syncthreads();
        float s = sm.pb.red[0]+sm.pb.red[1]+sm.pb.red[2]+sm.pb.red[3];
        float rinv = frcp(s);
        const int el4 = tid&7, ts = tid>>3;
        float ax=0, ay=0, az=0, aw=0;
        #pragma unroll 8
        for (int j=0;j<16;++j){
          int t2 = ts*16 + j;
          float wv2 = sm.pb.l[t2];
          float4 e4 = ((const float4*)(encst + ((size_t)bA*kT + t2)*kHE + (size_t)ecB*32))[el4];
          ax += wv2*e4.x; ay += wv2*e4.y; az += wv2*e4.z; aw += wv2*e4.w;
        }
        float4 r4; r4.x = ax*rinv; r4.y = ay*rinv; r4.z = az*rinv; r4.w = aw*rinv;
        sm.pb.cb[ts][el4] = r4;
        __syncthreads();
        if (tid < 32){
          int e4i = tid>>2, c = tid&3;
          float s2 = 0.f;
          #pragma unroll
          for (int ts2=0; ts2<32; ++ts2) s2 += ((const float*)&sm.pb.cb[ts2][e4i])[c];
          ctxb[(size_t)p*kB*kHE + (size_t)bA*kHE + ecB*32 + tid] = s2;
        }
      }
      fullbar(ctr);
      // ---- phase C: decoder LSTM cell (K=1024 via combined weights) ----
      {
        float a0=0,a1=0,a2=0,a3=0;
        for (int kc=0; kc<4; ++kc){
          #pragma unroll
          for (int i2=0;i2<4;++i2){
            int qq = tid + i2*256;
            int part = qq>>9, row = (qq>>5)&15, qi = qq&31;
            const float* src = part ? (hdec + (size_t)p*kB*kHD) : (ctxb + (size_t)p*kB*kHE);
            float4 v2 = ((const float4*)(src + (size_t)(bgC*16+row)*kHE + kc*128))[qi];
            *((float4*)(&sm.pc.xt[part][row][qi*4])) = v2;
          }
          __syncthreads();
          const float4* xv = (const float4*)(&sm.pc.xt[ksC][b_lC][0]);
          #pragma unroll 8
          for (int q=0;q<32;++q){
            float4 w = wrC[ksC*128 + kc*32 + q];
            float4 v2 = xv[q];
            a0 += w.x*v2.x; a1 += w.y*v2.y; a2 += w.z*v2.z; a3 += w.w*v2.w;
          }
          __syncthreads();
        }
        sm.pc.zb[col_l][ksC] = (a0+a1)+(a2+a3);
        __syncthreads();
        if (tid < 32){
          int base = (tid>>1)*8 + (tid&1);
          int e = e0c + (tid&1);
          int b2 = bgC*16 + (tid>>1);
          float zi = sm.pc.zb[base+0][0] + sm.pc.zb[base+0][1] + dbias[e];
          float zf = sm.pc.zb[base+2][0] + sm.pc.zb[base+2][1] + dbias[512+e];
          float zg = sm.pc.zb[base+4][0] + sm.pc.zb[base+4][1] + dbias[1024+e];
          float zo = sm.pc.zb[base+6][0] + sm.pc.zb[base+6][1] + dbias[1536+e];
          float c2 = fsig(zf)*cregD + fsig(zi)*ftanh(zg);
          cregD = c2;
          float h = fsig(zo)*ftanh(c2);
          hdec[(size_t)(p^1)*kB*kHD + (size_t)b2*kHD + e] = h;
          out[((size_t)b2*kT + t)*kHD + e] = h;
        }
      }
      mini_arrive(cCAa);
      p ^= 1;
    }
  }
}

extern "C" void kernel_launch(void* const* d_in, const int* in_sizes, int n_in,
                              void* d_out, int out_size, void* d_ws, size_t ws_size,
                              hipStream_t stream) {
  (void)in_sizes; (void)n_in; (void)out_size; (void)ws_size; // needs ws >= ~65 MB
  const float* x     = (const float*)d_in[0];
  const float* eWih  = (const float*)d_in[1];
  const float* eWhh  = (const float*)d_in[2];
  const float* eBih  = (const float*)d_in[3];
  const float* eBhh  = (const float*)d_in[4];
  const float* WencW = (const float*)d_in[5];
  const float* WencB = (const float*)d_in[6];
  const float* WdecW = (const float*)d_in[7];
  const float* WdecB = (const float*)d_in[8];
  const float* Vw    = (const float*)d_in[9];
  const float* attnB = (const float*)d_in[11];
  const float* dWih  = (const float*)d_in[12];
  const float* dWhh  = (const float*)d_in[13];
  const float* dBih  = (const float*)d_in[14];
  const float* dBhh  = (const float*)d_in[15];
  float* ws = (float*)d_ws;
  int* ctr = (int*)(ws + oEnd);
  hipMemsetAsync(ctr, 0, 1024, stream);
  hipLaunchKernelGGL(bahdanau_kernel, dim3(kNB), dim3(kNT), 0, stream,
                     x, eWih, eWhh, eBih, eBhh, WencW, WencB, WdecW, WdecB,
                     Vw, attnB, dWih, dWhh, dBih, dBhh,
                     (float*)d_out, ws, ctr);
}

// Round 2
// 68286.676 us; speedup vs baseline: 2.1059x; 2.1059x over previous
//
#include <hip/hip_runtime.h>
#include <stdint.h>

#define DEV __device__ __forceinline__

namespace {

constexpr int kT = 512, kB = 32, kF = 128, kHE = 512, kHD = 512, kA = 256;
constexpr int kNB = 512, kNT = 256;

typedef _Float16 f16;
typedef _Float16 h2 __attribute__((ext_vector_type(2)));
typedef _Float16 h4 __attribute__((ext_vector_type(4)));

// ---- workspace layout (float-unit offsets) ----
constexpr size_t oWencAll = 0;                              // float [2048][640]  = [Wih|Whh]
constexpr size_t oWdecH   = oWencAll + 2048ull*640;         // f16   [2048][1024] = [Wih_ctx | Wih_h+Whh]
constexpr size_t oWdWH    = oWdecH + 2048ull*1024/2;        // f16   [256][512]   = WdecW
constexpr size_t oEncSt   = oWdWH + 256ull*512/2;           // float [32][512][512]
constexpr size_t oEncPr   = oEncSt + (size_t)kB*kT*kHE;     // float [32*512][256]
constexpr size_t oHenc    = oEncPr + (size_t)kB*kT*kA;      // float [2][32][512]
constexpr size_t oHdec    = oHenc + 2ull*kB*kHE;            // float [3][32][512]
constexpr size_t oCtx     = oHdec + 3ull*kB*kHD;            // float [3][32][512]  (unnormalized, scaled 1/64)
constexpr size_t oDen     = oCtx + 3ull*kB*kHE;             // float [3][32]
constexpr size_t oScp     = oDen + 96;                      // float [32][16][256] dscore partials
constexpr size_t oEbias   = oScp + (size_t)kB*16*kA;        // 2048
constexpr size_t oDbias   = oEbias + 2048;                  // 2048
constexpr size_t oAb2     = oDbias + 2048;                  // 256 (Wdec_b + attn_bias)
constexpr size_t oEnd     = oAb2 + 256;
// ints at ws+oEnd: [0..31] fullbar grp, [32] root, [33] gen, [34] abort,
// [40..43] ENC, [48..79] AB1, [112..143] CA, [144..145] CTX

constexpr float kScale = 1.0f/64.0f;   // keeps unnormalized ctx within fp16 range; cancels in normalize

struct SmemEnc { float xh[8][644]; float w[16][644]; float zbuf[256][2]; float zs[8][4][4]; };
struct SA  { float h[32]; float sc[256]; float lw[32]; };
struct SC  { f16 xt[16][264]; float zb[128][2]; };
struct SEP { float4 et[32][32]; };
struct SmemDec {
  f16 epr[32][272];    // enc_proj slice (rows t0a..+32), fp16
  f16 est2[32][516];   // enc_states t-slice (rows t0a..+32, all 512 e), fp16
  float v[256];
  union { SA a; SC c; SEP ep; } u;
};
union Smem { SmemEnc enc; SmemDec dec; };

DEV float frcp(float x){ return __builtin_amdgcn_rcpf(x); }
DEV float fsig(float x){ return frcp(1.f + __expf(-x)); }
DEV float ftanh(float x){ return 1.f - 2.f*frcp(__expf(2.f*x) + 1.f); }

// relaxed agent-scope (MALL-coherent, no cache flush) accessors
DEV float ld_na(const float* p){ return __hip_atomic_load((float*)p, __ATOMIC_RELAXED, __HIP_MEMORY_SCOPE_AGENT); }
DEV void  st_na(float* p, float v){ __hip_atomic_store(p, v, __ATOMIC_RELAXED, __HIP_MEMORY_SCOPE_AGENT); }
DEV int   ld_ni(int* p){ return __hip_atomic_load(p, __ATOMIC_RELAXED, __HIP_MEMORY_SCOPE_AGENT); }

DEV void spin_ge(int* p, int tgt, int* abortf){
  int g = 0;
  while (ld_ni(p) < tgt){
    if (ld_ni(abortf) != 0) break;
    if (++g > (1<<21)){ __hip_atomic_store(abortf, 1, __ATOMIC_RELAXED, __HIP_MEMORY_SCOPE_AGENT); break; }
    __builtin_amdgcn_s_sleep(1);
  }
}
// lightweight: __syncthreads drains each wave's vmcnt (incl. sc-stores/atomics) before arrive
DEV void lw_bar(int* p, int tgt, int* abortf){
  __syncthreads();
  if (threadIdx.x == 0){
    __hip_atomic_fetch_add(p, 1, __ATOMIC_RELAXED, __HIP_MEMORY_SCOPE_AGENT);
    spin_ge(p, tgt, abortf);
  }
  __syncthreads();
}
DEV void lw_wait(int* p, int tgt, int* abortf){
  __syncthreads();
  if (threadIdx.x == 0) spin_ge(p, tgt, abortf);
  __syncthreads();
}
DEV void lw_arrive(int* p){
  __syncthreads();
  if (threadIdx.x == 0) __hip_atomic_fetch_add(p, 1, __ATOMIC_RELAXED, __HIP_MEMORY_SCOPE_AGENT);
}

// heavyweight 512-block barrier (3 uses total) — full fence for cached-data handoff
DEV void fullbar(int* ctr){
  __syncthreads();
  if (threadIdx.x == 0){
    int* gcnt = ctr; int* root = ctr+32; int* gen = ctr+33; int* abortf = ctr+34;
    int g = __hip_atomic_load(gen, __ATOMIC_RELAXED, __HIP_MEMORY_SCOPE_AGENT);
    __threadfence();
    int grp = blockIdx.x >> 4;
    bool last = false;
    if (__hip_atomic_fetch_add(&gcnt[grp], 1, __ATOMIC_ACQ_REL, __HIP_MEMORY_SCOPE_AGENT) == 15){
      __hip_atomic_store(&gcnt[grp], 0, __ATOMIC_RELAXED, __HIP_MEMORY_SCOPE_AGENT);
      if (__hip_atomic_fetch_add(root, 1, __ATOMIC_ACQ_REL, __HIP_MEMORY_SCOPE_AGENT) == 31){
        __hip_atomic_store(root, 0, __ATOMIC_RELAXED, __HIP_MEMORY_SCOPE_AGENT);
        __hip_atomic_fetch_add(gen, 1, __ATOMIC_RELEASE, __HIP_MEMORY_SCOPE_AGENT);
        last = true;
      }
    }
    if (!last){
      int gd = 0;
      while (__hip_atomic_load(gen, __ATOMIC_ACQUIRE, __HIP_MEMORY_SCOPE_AGENT) == g){
        if (__hip_atomic_load(abortf, __ATOMIC_RELAXED, __HIP_MEMORY_SCOPE_AGENT) != 0) break;
        if (++gd > (1<<21)){ __hip_atomic_store(abortf, 1, __ATOMIC_RELAXED, __HIP_MEMORY_SCOPE_AGENT); break; }
        __builtin_amdgcn_s_sleep(2);
      }
    }
    __threadfence();
  }
  __syncthreads();
}

} // namespace

__global__ __launch_bounds__(kNT, 2) void bahdanau_kernel(
    const float* __restrict__ x,
    const float* __restrict__ eWih, const float* __restrict__ eWhh,
    const float* __restrict__ eBih, const float* __restrict__ eBhh,
    const float* __restrict__ WencW, const float* __restrict__ WencB,
    const float* __restrict__ WdecW, const float* __restrict__ WdecB,
    const float* __restrict__ Vw, const float* __restrict__ attnB,
    const float* __restrict__ dWih, const float* __restrict__ dWhh,
    const float* __restrict__ dBih, const float* __restrict__ dBhh,
    float* __restrict__ out, float* __restrict__ ws, int* __restrict__ ctr)
{
  __shared__ Smem sm;
  const int tid = threadIdx.x;
  const int bid = blockIdx.x;

  float* wencall = ws + oWencAll;
  f16*   wdech   = (f16*)(ws + oWdecH);
  f16*   wdwh    = (f16*)(ws + oWdWH);
  float* encst   = ws + oEncSt;
  float* encpr   = ws + oEncPr;
  float* henc    = ws + oHenc;
  float* hdec    = ws + oHdec;
  float* ctxb    = ws + oCtx;
  float* den     = ws + oDen;
  float* scp     = ws + oScp;
  float* ebias   = ws + oEbias;
  float* dbias   = ws + oDbias;
  float* ab2w    = ws + oAb2;
  int* abortf    = ctr + 34;

  // ---------------- init ----------------
  {
    const int gid = bid*kNT + tid;
    const int stride = kNB*kNT;
    for (int i=gid; i<2048*640; i+=stride){
      int col = i/640, k = i - col*640;
      wencall[i] = (k < kF) ? eWih[col*kF + k] : eWhh[(size_t)col*kHE + (k-kF)];
    }
    for (int i=gid; i<2048*1024; i+=stride){
      int col = i>>10, k = i&1023;
      float v2 = dWih[((size_t)col<<10) + k];
      if (k >= 512) v2 += dWhh[((size_t)col<<9) + (k-512)];
      wdech[i] = (f16)v2;
    }
    for (int i=gid; i<256*512; i+=stride) wdwh[i] = (f16)WdecW[i];
    for (int i=gid; i<2048; i+=stride){ ebias[i] = eBih[i]+eBhh[i]; dbias[i] = dBih[i]+dBhh[i]; }
    for (int i=gid; i<256; i+=stride){ ab2w[i] = WdecB[i]+attnB[i]; }
    for (int i=gid; i<kB*kHE; i+=stride) henc[i] = 0.f;
    for (int i=gid; i<3*kB*kHE; i+=stride) ctxb[i] = 0.f;
    for (int i=gid; i<96; i+=stride) den[i] = 0.f;
    for (int i=gid; i<kB*kHD; i+=stride){
      int e = i & 511;
      float zi = dBih[e]+dBhh[e];
      float zg = dBih[1024+e]+dBhh[1024+e];
      float zo = dBih[1536+e]+dBhh[1536+e];
      float c0 = fsig(zi)*ftanh(zg);
      hdec[i] = fsig(zo)*ftanh(c0);   // buffer-0 initial decoder h
    }
  }
  fullbar(ctr);

  // ---------------- encoder: 512 steps ----------------
  {
    const int bg = bid >> 7, ec = bid & 127;
    const int b0 = bg*8, e0 = ec*4;
    const int ks  = tid >> 7;
    const int r   = tid & 127;
    const int e_l = r & 3, gate = (r>>2)&3, b_l = r>>4;
    const int srow = tid >> 5, sj = tid & 31;
    // LDS-resident weight slab: 16 cols x 640
    for (int i=tid; i<16*640; i+=kNT){
      int rr = i/640, k = i - rr*640;
      int g2 = rr>>2, el2 = rr&3;
      sm.enc.w[rr][k] = wencall[(size_t)(g2*kHE + e0 + el2)*640 + k];
    }
    __syncthreads();
    const float4* wv_base = (const float4*)(&sm.enc.w[gate*4+e_l][0]) + ks*80;
    int p = 0;
    float creg = 0.f;
    for (int t=0; t<kT; ++t){
      { // stage [x_t ; h_{t-1}] for 8 rows (h via MALL-coherent loads)
        const float4* xsrc = (const float4*)(x) + ((size_t)(b0+srow)*kT + t)*32;
        float4* dst = (float4*)(&sm.enc.xh[srow][0]);
        dst[sj] = xsrc[sj];
        const float* hsrc = henc + (size_t)p*kB*kHE + (size_t)(b0+srow)*kHE;
        #pragma unroll
        for (int it=0; it<4; ++it){
          int c0 = 4*(sj + 32*it);
          float4 hv;
          hv.x = ld_na(hsrc+c0); hv.y = ld_na(hsrc+c0+1);
          hv.z = ld_na(hsrc+c0+2); hv.w = ld_na(hsrc+c0+3);
          *(float4*)(&sm.enc.xh[srow][128+c0]) = hv;
        }
      }
      __syncthreads();
      {
        const float4* xv = (const float4*)(&sm.enc.xh[b_l][0]) + ks*80;
        float a0=0,a1=0,a2=0,a3=0;
        #pragma unroll 8
        for (int q=0;q<80;++q){
          float4 w = wv_base[q]; float4 v2 = xv[q];
          a0 += w.x*v2.x; a1 += w.y*v2.y; a2 += w.z*v2.z; a3 += w.w*v2.w;
        }
        sm.enc.zbuf[r][ks] = (a0+a1)+(a2+a3);
      }
      __syncthreads();
      if (tid < 128){
        float z = sm.enc.zbuf[tid][0] + sm.enc.zbuf[tid][1] + ebias[gate*kHE + e0 + e_l];
        sm.enc.zs[b_l][gate][e_l] = z;
      }
      __syncthreads();
      if (tid < 32){
        int bl2 = tid>>2, el2 = tid&3;
        float zi = sm.enc.zs[bl2][0][el2];
        float zf = sm.enc.zs[bl2][1][el2];
        float zg = sm.enc.zs[bl2][2][el2];
        float zo = sm.enc.zs[bl2][3][el2];
        float c2 = fsig(zf)*creg + fsig(zi)*ftanh(zg);
        creg = c2;
        float h = fsig(zo)*ftanh(c2);
        int b = b0 + bl2, e = e0 + el2;
        st_na(&henc[(size_t)(p^1)*kB*kHE + (size_t)b*kHE + e], h);
        encst[((size_t)b*kT + t)*kHE + e] = h;   // plain; published by fullbar
      }
      lw_bar(&ctr[40+bg], 128*(t+1), abortf);
      p ^= 1;
    }
  }
  fullbar(ctr);

  // ---------------- enc_proj = enc_states @ Wenc^T + b ----------------
  {
    const int r0 = bid*32;
    const int a = tid;
    float acc[32];
    #pragma unroll
    for (int i=0;i<32;++i) acc[i]=0.f;
    for (int kt=0; kt<4; ++kt){
      #pragma unroll
      for (int i2=0;i2<4;++i2){
        int q = tid + i2*256;
        int row = q>>5, qi = q&31;
        sm.dec.u.ep.et[row][qi] = ((const float4*)(encst + ((size_t)(r0+row))*kHE + kt*128))[qi];
      }
      __syncthreads();
      const float4* wv = (const float4*)(WencW + (size_t)a*kHE + kt*128);
      #pragma unroll 1
      for (int q=0;q<32;++q){
        float4 w = wv[q];
        #pragma unroll
        for (int i=0;i<32;++i){
          float4 e4 = sm.dec.u.ep.et[i][q];
          acc[i] += e4.x*w.x + e4.y*w.y + e4.z*w.z + e4.w*w.w;
        }
      }
      __syncthreads();
    }
    float bb = WencB[a];
    #pragma unroll
    for (int i=0;i<32;++i) encpr[((size_t)(r0+i))*kA + a] = acc[i] + bb;
  }
  fullbar(ctr);

  // ---------------- decoder: 512 steps, 3 lightweight syncs/step ----------------
  {
    const int bA = bid >> 4, tc = bid & 15, t0a = tc*32;     // A-role: (batch, t-chunk)
    const int half = bid >> 8, ecp = bid & 255, e0c = ecp*2; // C-role: (b-half, e-pair)
    const int col_l = tid & 127, ksC = tid >> 7;
    const int e_lC = col_l & 1, gateC = (col_l>>1)&3, b_lC = col_l>>3;
    const int colC = gateC*kHD + e0c + e_lC;
    const f16* wrC = wdech + (size_t)colC*1024;
    int* cCAw = &ctr[112 + half*16 + tc];
    int* cCAa = &ctr[112 + half*16 + (ecp>>4)];
    int* cAB1 = &ctr[48 + bA];
    int* cCTX = &ctr[144 + half];

    // one-time LDS residents (fp16)
    for (int i=tid; i<32*256; i+=kNT){
      int rr = i>>8, c = i&255;
      sm.dec.epr[rr][c] = (f16)encpr[((size_t)bA*kT + t0a + rr)*kA + c];
    }
    for (int i=tid; i<32*512; i+=kNT){
      int rr = i>>9, c = i&511;
      sm.dec.est2[rr][c] = (f16)encst[((size_t)bA*kT + t0a + rr)*kHE + c];
    }
    sm.dec.v[tid] = Vw[tid];
    const float ab2r = ab2w[tid];
    float cregD=0, dbi=0, dbf=0, dbg=0, dbo=0;
    if (tid < 32){
      int e = e0c + (tid&1);
      dbi = dbias[e]; dbf = dbias[512+e]; dbg = dbias[1024+e]; dbo = dbias[1536+e];
      cregD = fsig(dbi)*ftanh(dbg);
    }
    __syncthreads();

    int r = 0;
    for (int t=0; t<kT; ++t){
      const int rn = (r==2) ? 0 : r+1;
      // ---- A: wait h, dscore partial ----
      lw_wait(cCAw, 16*t, abortf);
      if (tid < 32) sm.dec.u.a.h[tid] = ld_na(hdec + (size_t)r*kB*kHD + (size_t)bA*kHD + t0a + tid);
      __syncthreads();
      {
        const h4* wv = (const h4*)(wdwh + (size_t)tid*kHD + t0a);
        float sp = 0.f;
        #pragma unroll
        for (int q=0;q<8;++q){
          h4 w = wv[q];
          sp += (float)w.x*sm.dec.u.a.h[q*4+0] + (float)w.y*sm.dec.u.a.h[q*4+1]
              + (float)w.z*sm.dec.u.a.h[q*4+2] + (float)w.w*sm.dec.u.a.h[q*4+3];
        }
        st_na(&scp[((size_t)bA*16 + tc)*kA + tid], sp);
      }
      lw_bar(cAB1, 16*(t+1), abortf);
      // ---- B: full dscore, logits, exp, unnormalized ctx partial ----
      {
        float sc = ab2r;
        #pragma unroll
        for (int j=0;j<16;++j) sc += ld_na(&scp[((size_t)bA*16 + j)*kA + tid]);
        sm.dec.u.a.sc[tid] = sc;
      }
      __syncthreads();
      {
        const int tl = tid>>3, as = tid&7;
        float acc = 0.f;
        #pragma unroll
        for (int q=0;q<8;++q){
          int a0 = q*32 + as*4;
          h4 e4 = *(const h4*)(&sm.dec.epr[tl][a0]);
          acc += sm.dec.v[a0+0]*ftanh((float)e4.x + sm.dec.u.a.sc[a0+0]);
          acc += sm.dec.v[a0+1]*ftanh((float)e4.y + sm.dec.u.a.sc[a0+1]);
          acc += sm.dec.v[a0+2]*ftanh((float)e4.z + sm.dec.u.a.sc[a0+2]);
          acc += sm.dec.v[a0+3]*ftanh((float)e4.w + sm.dec.u.a.sc[a0+3]);
        }
        acc += __shfl_down(acc, 4, 8);
        acc += __shfl_down(acc, 2, 8);
        acc += __shfl_down(acc, 1, 8);
        if (as == 0) sm.dec.u.a.lw[tl] = __expf(acc) * kScale;
      }
      __syncthreads();
      {
        // partial ctx over local 32 t-rows for all 512 e, into rotating buffer r
        const int e0p = 2*tid;
        float c0=0.f, c1=0.f;
        #pragma unroll 8
        for (int j=0;j<32;++j){
          float w = sm.dec.u.a.lw[j];
          h2 ev = *(const h2*)(&sm.dec.est2[j][e0p]);
          c0 += w*(float)ev.x; c1 += w*(float)ev.y;
        }
        float* cdst = ctxb + (size_t)r*kB*kHE + (size_t)bA*kHE;
        atomicAdd(&cdst[e0p], c0);
        atomicAdd(&cdst[e0p+1], c1);
        if (tid == 0){
          float ds = 0.f;
          #pragma unroll
          for (int j=0;j<32;++j) ds += sm.dec.u.a.lw[j];
          atomicAdd(&den[r*kB + bA], ds);
        }
        // zero next-next rotation slice (last read at step t-2 — safe)
        float* znext = ctxb + (size_t)rn*kB*kHE + (size_t)bA*kHE;
        st_na(&znext[e0p], 0.f); st_na(&znext[e0p+1], 0.f);
        if (tid == 0) st_na(&den[rn*kB + bA], 0.f);
      }
      lw_bar(cCTX, 256*(t+1), abortf);
      // ---- C: decoder LSTM cell, normalize ctx inside dot ----
      {
        const float rv = frcp(ld_na(&den[r*kB + half*16 + b_lC]));
        float a0c=0,a1c=0,a2c=0,a3c=0, a0h=0,a1h=0,a2h=0,a3h=0;
        const int rowS = tid>>4, c16 = (tid&15)*16;
        for (int kc=0; kc<4; ++kc){
          const float* src = ((kc<2) ? (ctxb + (size_t)r*kB*kHE) : (hdec + (size_t)r*kB*kHD))
                             + (size_t)(half*16 + rowS)*512 + (kc&1)*256 + c16;
          float f[16];
          #pragma unroll
          for (int j=0;j<16;++j) f[j] = ld_na(src+j);
          #pragma unroll
          for (int g=0; g<4; ++g){
            h4 hv; hv.x=(f16)f[4*g]; hv.y=(f16)f[4*g+1]; hv.z=(f16)f[4*g+2]; hv.w=(f16)f[4*g+3];
            *(h4*)(&sm.dec.u.c.xt[rowS][c16 + 4*g]) = hv;
          }
          __syncthreads();
          const h4* wc = (const h4*)(wrC) + kc*64 + ksC*32;
          const h4* xv = (const h4*)(&sm.dec.u.c.xt[b_lC][ksC*128]);
          if (kc < 2){
            #pragma unroll 8
            for (int q=0;q<32;++q){
              h4 w = wc[q]; h4 xvv = xv[q];
              a0c += (float)w.x*(float)xvv.x; a1c += (float)w.y*(float)xvv.y;
              a2c += (float)w.z*(float)xvv.z; a3c += (float)w.w*(float)xvv.w;
            }
          } else {
            #pragma unroll 8
            for (int q=0;q<32;++q){
              h4 w = wc[q]; h4 xvv = xv[q];
              a0h += (float)w.x*(float)xvv.x; a1h += (float)w.y*(float)xvv.y;
              a2h += (float)w.z*(float)xvv.z; a3h += (float)w.w*(float)xvv.w;
            }
          }
          __syncthreads();
        }
        sm.dec.u.c.zb[col_l][ksC] = ((a0c+a1c)+(a2c+a3c))*rv + ((a0h+a1h)+(a2h+a3h));
        __syncthreads();
        if (tid < 32){
          int base = (tid>>1)*8 + (tid&1);
          int e = e0c + (tid&1), b2 = half*16 + (tid>>1);
          float zi = sm.dec.u.c.zb[base+0][0] + sm.dec.u.c.zb[base+0][1] + dbi;
          float zf = sm.dec.u.c.zb[base+2][0] + sm.dec.u.c.zb[base+2][1] + dbf;
          float zg = sm.dec.u.c.zb[base+4][0] + sm.dec.u.c.zb[base+4][1] + dbg;
          float zo = sm.dec.u.c.zb[base+6][0] + sm.dec.u.c.zb[base+6][1] + dbo;
          float c2 = fsig(zf)*cregD + fsig(zi)*ftanh(zg);
          cregD = c2;
          float h = fsig(zo)*ftanh(c2);
          st_na(&hdec[(size_t)rn*kB*kHD + (size_t)b2*kHD + e], h);
          out[((size_t)b2*kT + t)*kHD + e] = h;
        }
      }
      lw_arrive(cCAa);
      r = rn;
    }
  }
}

extern "C" void kernel_launch(void* const* d_in, const int* in_sizes, int n_in,
                              void* d_out, int out_size, void* d_ws, size_t ws_size,
                              hipStream_t stream) {
  (void)in_sizes; (void)n_in; (void)out_size; (void)ws_size; // needs ws >= ~62 MB
  const float* x     = (const float*)d_in[0];
  const float* eWih  = (const float*)d_in[1];
  const float* eWhh  = (const float*)d_in[2];
  const float* eBih  = (const float*)d_in[3];
  const float* eBhh  = (const float*)d_in[4];
  const float* WencW = (const float*)d_in[5];
  const float* WencB = (const float*)d_in[6];
  const float* WdecW = (const float*)d_in[7];
  const float* WdecB = (const float*)d_in[8];
  const float* Vw    = (const float*)d_in[9];
  const float* attnB = (const float*)d_in[11];
  const float* dWih  = (const float*)d_in[12];
  const float* dWhh  = (const float*)d_in[13];
  const float* dBih  = (const float*)d_in[14];
  const float* dBhh  = (const float*)d_in[15];
  float* ws = (float*)d_ws;
  int* ctr = (int*)(ws + oEnd);
  hipMemsetAsync(ctr, 0, 1024, stream);
  hipLaunchKernelGGL(bahdanau_kernel, dim3(kNB), dim3(kNT), 0, stream,
                     x, eWih, eWhh, eBih, eBhh, WencW, WencB, WdecW, WdecB,
                     Vw, attnB, dWih, dWhh, dBih, dBhh,
                     (float*)d_out, ws, ctr);
}